// Round 1
// baseline (83.505 us; speedup 1.0000x reference)
//
#include <hip/hip_runtime.h>

// MusicalConstraintLoss: tokens [B=512, S=16384] int32 (harness converts int64->int32).
//   rhythm  = 0.01 * var(gaps between consecutive time tokens, ddof=1, pooled)
//   harmony = 0.1  * count(adjacent note pairs with |pc diff|==6) / (B*S)
//   voice   = count(consecutive-note leaps |dv|>12) / B
//   total   = rhythm + harmony + 0.5*voice
// Exact integer accumulation (n, sum_d, sum_d2 int64), final math in double.

#define BATCH 512
#define SEQ   16384
#define TPB   1024
#define EPT   (SEQ / TPB)   // 16 contiguous elements per thread
#define NWAVES (TPB / 64)   // 16

__global__ __launch_bounds__(TPB) void
mcl_scan_kernel(const int* __restrict__ tokens,
                int* __restrict__ ct_a, int* __restrict__ sd_a,
                long long* __restrict__ sd2_a,
                int* __restrict__ harm_a, int* __restrict__ leap_a)
{
    const int row  = blockIdx.x;
    const int t    = threadIdx.x;
    const int lane = t & 63;
    const int wave = t >> 6;

    __shared__ int s_first[TPB];        // each thread's first element (halo for harmony)
    __shared__ int s_time[NWAVES];      // per-wave inclusive max of last_time
    __shared__ int s_note[NWAVES];      // per-wave inclusive max of note pack
    __shared__ long long s_red[NWAVES][5];

    const int* rowp = tokens + (size_t)row * SEQ;
    const int  base = t * EPT;

    // ---- load 16 contiguous ints via 4x int4 (each lane consumes one full 64B line) ----
    int e[EPT];
    const int4* v = (const int4*)(rowp + base);
#pragma unroll
    for (int j = 0; j < EPT / 4; ++j) {
        int4 x = v[j];
        e[4*j+0] = x.x; e[4*j+1] = x.y; e[4*j+2] = x.z; e[4*j+3] = x.w;
    }
    s_first[t] = e[0];
    __syncthreads();
    const int enext = (t + 1 < TPB) ? s_first[t + 1] : -1;   // halo (row end: none)

    // ---- local sequential scan over the 16-element segment ----
    int ct = 0, sd = 0, harm = 0, leaps = 0;
    long long sd2 = 0;
    int first_time = -1, last_time = -1;
    int first_note_val = -1, last_note_pos = -1, last_note_val = 0;

#pragma unroll
    for (int j = 0; j < EPT; ++j) {
        const int tok = e[j];
        const int pos = base + j;
        const bool is_time = (tok >= 256) && (tok < 768);
        const bool is_note = (tok < 128);
        if (is_time) {
            if (last_time >= 0) {
                int d = pos - last_time;
                ct++; sd += d; sd2 += (long long)d * d;
            } else first_time = pos;
            last_time = pos;
        }
        if (is_note) {
            if (last_note_pos >= 0) {
                int itv = tok - last_note_val;
                if (itv > 12 || itv < -12) leaps++;
            } else first_note_val = tok;
            last_note_pos = pos; last_note_val = tok;
        }
        const int nb = (j < EPT - 1) ? e[j + 1] : enext;
        if (is_note && (unsigned)nb < 128u) {
            int d = tok % 12 - nb % 12;
            if (d == 6 || d == -6) harm++;
        }
    }

    // ---- block-wide exclusive max-scan: predecessor time-pos and note (pos<<10|val) ----
    int note_pack = (last_note_pos >= 0) ? ((last_note_pos << 10) | last_note_val) : -1;
    int lt = last_time, np = note_pack;
#pragma unroll
    for (int off = 1; off < 64; off <<= 1) {
        int a = __shfl_up(lt, off);
        int b = __shfl_up(np, off);
        if (lane >= off) { lt = max(lt, a); np = max(np, b); }
    }
    int excl_t = __shfl_up(lt, 1);
    int excl_n = __shfl_up(np, 1);
    if (lane == 0) { excl_t = -1; excl_n = -1; }
    if (lane == 63) { s_time[wave] = lt; s_note[wave] = np; }
    __syncthreads();
    int pt = -1, pn = -1;
    for (int w = 0; w < wave; ++w) {      // <=15 iters, wave-uniform
        pt = max(pt, s_time[w]);
        pn = max(pn, s_note[w]);
    }
    const int prev_time = max(pt, excl_t);
    const int prev_note = max(pn, excl_n);

    if (first_time >= 0 && prev_time >= 0) {
        int d = first_time - prev_time;
        ct++; sd += d; sd2 += (long long)d * d;
    }
    if (first_note_val >= 0 && prev_note >= 0) {
        int itv = first_note_val - (prev_note & 1023);
        if (itv > 12 || itv < -12) leaps++;
    }

    // ---- block reduce the 5 accumulators ----
#pragma unroll
    for (int off = 32; off; off >>= 1) {
        ct    += __shfl_down(ct, off);
        sd    += __shfl_down(sd, off);
        sd2   += __shfl_down(sd2, off);
        harm  += __shfl_down(harm, off);
        leaps += __shfl_down(leaps, off);
    }
    __syncthreads();   // s_first/s_time reuse barrier (defensive; distinct arrays anyway)
    if (lane == 0) {
        s_red[wave][0] = ct;   s_red[wave][1] = sd;  s_red[wave][2] = sd2;
        s_red[wave][3] = harm; s_red[wave][4] = leaps;
    }
    __syncthreads();
    if (t == 0) {
        long long a0 = 0, a1 = 0, a2 = 0, a3 = 0, a4 = 0;
        for (int w = 0; w < NWAVES; ++w) {
            a0 += s_red[w][0]; a1 += s_red[w][1]; a2 += s_red[w][2];
            a3 += s_red[w][3]; a4 += s_red[w][4];
        }
        ct_a[row]   = (int)a0;
        sd_a[row]   = (int)a1;   // per-row sum of gaps <= SEQ, fits int
        sd2_a[row]  = a2;        // per-row <= SEQ^2 ~ 2.7e8, global needs 64-bit
        harm_a[row] = (int)a3;
        leap_a[row] = (int)a4;
    }
}

__global__ __launch_bounds__(512) void
mcl_final_kernel(const int* __restrict__ ct_a, const int* __restrict__ sd_a,
                 const long long* __restrict__ sd2_a,
                 const int* __restrict__ harm_a, const int* __restrict__ leap_a,
                 float* __restrict__ out)
{
    const int t = threadIdx.x;
    const int lane = t & 63, wave = t >> 6;
    long long ct = ct_a[t], sd = sd_a[t], sd2 = sd2_a[t];
    long long harm = harm_a[t], leaps = leap_a[t];
#pragma unroll
    for (int off = 32; off; off >>= 1) {
        ct   += __shfl_down(ct, off);
        sd   += __shfl_down(sd, off);
        sd2  += __shfl_down(sd2, off);
        harm += __shfl_down(harm, off);
        leaps+= __shfl_down(leaps, off);
    }
    __shared__ long long s[8][5];
    if (lane == 0) { s[wave][0]=ct; s[wave][1]=sd; s[wave][2]=sd2; s[wave][3]=harm; s[wave][4]=leaps; }
    __syncthreads();
    if (t == 0) {
        long long A = 0, Bs = 0, C = 0, D = 0, E = 0;
        for (int w = 0; w < 8; ++w) { A+=s[w][0]; Bs+=s[w][1]; C+=s[w][2]; D+=s[w][3]; E+=s[w][4]; }
        double n = (double)A;
        double rhythm = 0.0;
        if (A > 1) {
            double mean = (double)Bs / n;
            double ss   = (double)C - (double)Bs * mean;   // sum d^2 - n*mean^2
            rhythm = 0.01 * ss / (n - 1.0);
        }
        double harmony = 0.1 * (double)D / ((double)BATCH * (double)SEQ);
        double voice   = (double)E / (double)BATCH;
        out[0] = (float)rhythm;
        out[1] = (float)harmony;
        out[2] = (float)voice;
        out[3] = (float)(rhythm + harmony + 0.5 * voice);
    }
}

extern "C" void kernel_launch(void* const* d_in, const int* in_sizes, int n_in,
                              void* d_out, int out_size, void* d_ws, size_t ws_size,
                              hipStream_t stream)
{
    const int* tokens = (const int*)d_in[0];
    float* out = (float*)d_out;

    char* ws = (char*)d_ws;
    long long* sd2_a  = (long long*)ws;              // 512 * 8 = 4096 B
    int*       ct_a   = (int*)(ws + 4096);           // 2048 B
    int*       sd_a   = (int*)(ws + 6144);           // 2048 B
    int*       harm_a = (int*)(ws + 8192);           // 2048 B
    int*       leap_a = (int*)(ws + 10240);          // 2048 B

    mcl_scan_kernel<<<BATCH, TPB, 0, stream>>>(tokens, ct_a, sd_a, sd2_a, harm_a, leap_a);
    mcl_final_kernel<<<1, 512, 0, stream>>>(ct_a, sd_a, sd2_a, harm_a, leap_a, out);
}